// Round 3
// baseline (235.597 us; speedup 1.0000x reference)
//
#include <hip/hip_runtime.h>

#define NROWS 8192
#define DDIM  256
#define KSPLIT 4
#define BM 128
#define BK 64
#define NT (NROWS / KSPLIT / BK)   // 32 tiles per split

typedef __bf16 bf16x8 __attribute__((ext_vector_type(8)));
typedef float  f32x4  __attribute__((ext_vector_type(4)));

typedef __attribute__((address_space(1))) unsigned int uint_gas;
typedef __attribute__((address_space(3))) unsigned int uint_las;

__device__ __forceinline__ void gload_lds16(const void* g, void* l) {
  __builtin_amdgcn_global_load_lds((const uint_gas*)g, (uint_las*)l, 16, 0, 0);
}

__device__ __forceinline__ unsigned int f2bf_bits(float f) {
  union { float f; unsigned int u; } v; v.f = f;
  unsigned int r = v.u + 0x7FFFu + ((v.u >> 16) & 1u);
  return r >> 16;
}
__device__ __forceinline__ float bf2f(unsigned int b) {
  union { unsigned int u; float f; } v; v.u = b << 16;
  return v.f;
}

// ---------------- kernel 0: fp32 -> bf16 conversion (weights only) ----------------
__global__ __launch_bounds__(256) void convert_kernel(
    const float* __restrict__ wq, const float* __restrict__ wk,
    const float* __restrict__ wv, unsigned short* __restrict__ Wb)
{
  int i = blockIdx.x * 256 + threadIdx.x;
  const int nw4 = DDIM * DDIM / 4;   // 16384
  const float4* src; int j;
  if (i < nw4)          { src = (const float4*)wq; j = i; }
  else if (i < 2*nw4)   { src = (const float4*)wk; j = i - nw4; }
  else                  { src = (const float4*)wv; j = i - 2*nw4; }
  float4 f = src[j];
  ushort4 o;
  o.x = (unsigned short)f2bf_bits(f.x);
  o.y = (unsigned short)f2bf_bits(f.y);
  o.z = (unsigned short)f2bf_bits(f.z);
  o.w = (unsigned short)f2bf_bits(f.w);
  ((ushort4*)(Wb))[i] = o;
}

// ---------------- kernel 1: QKV projections + L2 norm + vT ----------------
// grid = 384: out = bid/128 (0=q,1=k,2=v), mb = bid%128 (64-row slab)
__global__ __launch_bounds__(256) void qkv_kernel(
    const float* __restrict__ bq, const float* __restrict__ bk, const float* __restrict__ bv,
    const float* __restrict__ x, const unsigned short* __restrict__ Wb,
    unsigned short* __restrict__ qb, unsigned short* __restrict__ kb,
    unsigned short* __restrict__ vb, unsigned short* __restrict__ vT)
{
  __shared__ unsigned short vstage[DDIM * 72];
  const int t = threadIdx.x;
  const int w = t >> 6, l = t & 63;
  const int c = l & 15, g = l >> 4;
  const int out = blockIdx.x / 128;
  const int mb  = blockIdx.x % 128;
  const int row0 = mb * 64;
  const int rw = row0 + w * 16;

  // load x rows as fp32, convert to bf16 fragments in-register
  bf16x8 a[8];
  #pragma unroll
  for (int ks = 0; ks < 8; ks++) {
    const float* p = x + (size_t)(rw + c) * DDIM + ks * 32 + g * 8;
    float4 f0 = *(const float4*)p;
    float4 f1 = *(const float4*)(p + 4);
    union { bf16x8 v; unsigned short s[8]; } u;
    u.s[0] = (unsigned short)f2bf_bits(f0.x);
    u.s[1] = (unsigned short)f2bf_bits(f0.y);
    u.s[2] = (unsigned short)f2bf_bits(f0.z);
    u.s[3] = (unsigned short)f2bf_bits(f0.w);
    u.s[4] = (unsigned short)f2bf_bits(f1.x);
    u.s[5] = (unsigned short)f2bf_bits(f1.y);
    u.s[6] = (unsigned short)f2bf_bits(f1.z);
    u.s[7] = (unsigned short)f2bf_bits(f1.w);
    a[ks] = u.v;
  }

  const unsigned short* W = Wb + out * DDIM * DDIM;
  const float* bias = (out == 0) ? bq : (out == 1) ? bk : bv;
  unsigned short* dst = (out == 0) ? qb : (out == 1) ? kb : vb;
  f32x4 vals[16];
  #pragma unroll
  for (int ct = 0; ct < 16; ct++) {
    f32x4 acc = {0.f, 0.f, 0.f, 0.f};
    #pragma unroll
    for (int ks = 0; ks < 8; ks++) {
      bf16x8 b = *(const bf16x8*)(W + (size_t)(ct * 16 + c) * DDIM + ks * 32 + g * 8);
      acc = __builtin_amdgcn_mfma_f32_16x16x32_bf16(a[ks], b, acc, 0, 0, 0);
    }
    float bias_v = bias[ct * 16 + c];
    #pragma unroll
    for (int r = 0; r < 4; r++) acc[r] += bias_v;
    vals[ct] = acc;
  }
  if (out < 2) {   // L2 normalize rows (q, k)
    #pragma unroll
    for (int r = 0; r < 4; r++) {
      float ss = 0.f;
      #pragma unroll
      for (int ct = 0; ct < 16; ct++) ss += vals[ct][r] * vals[ct][r];
      ss += __shfl_xor(ss, 1); ss += __shfl_xor(ss, 2);
      ss += __shfl_xor(ss, 4); ss += __shfl_xor(ss, 8);
      float inv = 1.f / fmaxf(sqrtf(ss), 1e-12f);
      #pragma unroll
      for (int ct = 0; ct < 16; ct++) vals[ct][r] *= inv;
    }
  }
  #pragma unroll
  for (int ct = 0; ct < 16; ct++) {
    #pragma unroll
    for (int r = 0; r < 4; r++) {
      unsigned int bits = f2bf_bits(vals[ct][r]);
      unsigned int ob = (unsigned int)__shfl_xor((int)bits, 1);
      if (!(l & 1))
        *(unsigned int*)(dst + (size_t)(rw + g * 4 + r) * DDIM + ct * 16 + c) =
            bits | (ob << 16);
      if (out == 2)
        vstage[(ct * 16 + c) * 72 + (w * 16 + g * 4 + r)] = (unsigned short)bits;
    }
  }
  if (out == 2) {
    __syncthreads();
    #pragma unroll
    for (int p = 0; p < 8; p++) {
      int dd = (t >> 3) + p * 32;
      int ch = t & 7;
      *(uint4*)(vT + (size_t)dd * NROWS + row0 + ch * 8) =
          *(const uint4*)(vstage + dd * 72 + ch * 8);
    }
  }
}

// ---------------- kernel 2: fused relu-attention partials ----------------
// BM=128 q-rows/block, 8 waves as 2 row-groups x 4 col-groups.
// Per-wave S tile = 64 rows x 16 cols; PV tile = 64 rows x 64 d-cols.
__global__ __launch_bounds__(512, 2) void attn_kernel(
    const unsigned short* __restrict__ qb, const unsigned short* __restrict__ kb,
    const unsigned short* __restrict__ vT,
    float* __restrict__ nump, float* __restrict__ denp)
{
  // 2x32KB K dbuf | 2x32KB vT dbuf | 16KB P ([128][64] bf16, XOR-swizzled)
  __shared__ __align__(16) char smem[147456];
  char* kbuf = smem;
  char* vbuf = smem + 65536;
  char* P    = smem + 131072;

  const int t = threadIdx.x;
  const int w = t >> 6, l = t & 63;
  const int c = l & 15, g = l >> 4;
  const int wr = w >> 2, wc = w & 3;   // wr 0..1 (64 rows), wc 0..3 (16 S-cols / 64 d-cols)
  const int bid = blockIdx.x;
  const int split = bid & (KSPLIT - 1);
  const int mb = bid >> 2;
  const int q0 = mb * BM;
  const int kbase0 = split * (NROWS / KSPLIT);

  const char* kbc = (const char*)kb;
  const char* vtc = (const char*)vT;

  // hoist q fragments: 4 row-tiles x 8 k-steps = 128 VGPR
  bf16x8 qa[4][8];
  #pragma unroll
  for (int rt = 0; rt < 4; rt++)
    #pragma unroll
    for (int ks = 0; ks < 8; ks++)
      qa[rt][ks] = *(const bf16x8*)(qb + (size_t)(q0 + wr*64 + rt*16 + c) * DDIM + ks*32 + g*8);

  f32x4 oacc[4][4];
  #pragma unroll
  for (int rt = 0; rt < 4; rt++)
    #pragma unroll
    for (int dt = 0; dt < 4; dt++)
      oacc[rt][dt] = (f32x4){0.f, 0.f, 0.f, 0.f};
  float den[4][4];
  #pragma unroll
  for (int rt = 0; rt < 4; rt++)
    #pragma unroll
    for (int r = 0; r < 4; r++) den[rt][r] = 0.f;

  auto stage = [&](int buf, int it) {
    const int kbase = kbase0 + it * BK;
    const char* ksrc = kbc + (size_t)kbase * 512;
    #pragma unroll
    for (int i = 0; i < 4; i++) {
      int n = i * 512 + t;
      int row = n >> 5, slot = n & 31;
      gload_lds16(ksrc + row * 512 + ((slot ^ (row & 7)) * 16),
                  kbuf + buf * 32768 + i * 8192 + w * 1024);
    }
    const char* vsrc = vtc + (size_t)kbase * 2;
    #pragma unroll
    for (int i = 0; i < 4; i++) {
      int n = i * 512 + t;
      int dd = n >> 3, slot = n & 7;
      gload_lds16(vsrc + (size_t)dd * (NROWS * 2) + ((slot ^ (dd & 7)) * 16),
                  vbuf + buf * 32768 + i * 8192 + w * 1024);
    }
  };

  // prologue: stage tile 0 into buf 0
  stage(0, 0);
  asm volatile("s_waitcnt vmcnt(0)" ::: "memory");
  __builtin_amdgcn_sched_barrier(0);
  __builtin_amdgcn_s_barrier();
  __builtin_amdgcn_sched_barrier(0);

  for (int it = 0; it < NT; ++it) {
    const int cur = it & 1;
    if (it + 1 < NT) stage(cur ^ 1, it + 1);
    __builtin_amdgcn_sched_barrier(0);

    // ---- QK^T: this wave's 64 rows x 16 cols ----
    const char* kcur = kbuf + cur * 32768;
    f32x4 sacc[4];
    #pragma unroll
    for (int rt = 0; rt < 4; rt++) sacc[rt] = (f32x4){0.f, 0.f, 0.f, 0.f};
    const int rl = wc * 16 + c;
    __builtin_amdgcn_s_setprio(1);
    #pragma unroll
    for (int ks = 0; ks < 8; ks++) {
      bf16x8 kf = *(const bf16x8*)(kcur + rl * 512 + ((ks * 64 + g * 16) ^ ((rl & 7) << 4)));
      #pragma unroll
      for (int rt = 0; rt < 4; rt++)
        sacc[rt] = __builtin_amdgcn_mfma_f32_16x16x32_bf16(qa[rt][ks], kf, sacc[rt], 0, 0, 0);
    }
    __builtin_amdgcn_s_setprio(0);

    // relu, denominator accumulate, pack P to LDS (swizzled [128][64] bf16)
    #pragma unroll
    for (int rt = 0; rt < 4; rt++)
      #pragma unroll
      for (int r = 0; r < 4; r++) {
        float v = fmaxf(sacc[rt][r], 0.f);
        den[rt][r] += v;
        unsigned int bits = f2bf_bits(v);
        unsigned int ob = (unsigned int)__shfl_xor((int)bits, 1);
        if (!(l & 1)) {
          int prow = wr * 64 + rt * 16 + g * 4 + r;
          int pcol = wc * 16 + c;   // even
          *(unsigned int*)(P + prow * 128 + ((pcol * 2) ^ ((prow & 7) << 4))) =
              bits | (ob << 16);
        }
      }
    // P visibility barrier — LDS-only drain, prefetch loads stay in flight
    asm volatile("s_waitcnt lgkmcnt(0)" ::: "memory");
    __builtin_amdgcn_sched_barrier(0);
    __builtin_amdgcn_s_barrier();
    __builtin_amdgcn_sched_barrier(0);

    // ---- PV: this wave's 64 rows x 64 d-cols ----
    const char* vcur = vbuf + cur * 32768;
    #pragma unroll
    for (int ks2 = 0; ks2 < 2; ks2++) {
      bf16x8 pa[4];
      #pragma unroll
      for (int rt = 0; rt < 4; rt++) {
        int prow = wr * 64 + rt * 16 + c;
        pa[rt] = *(const bf16x8*)(P + prow * 128 +
                                  ((ks2 * 64 + g * 16) ^ ((prow & 7) << 4)));
      }
      __builtin_amdgcn_s_setprio(1);
      #pragma unroll
      for (int dt = 0; dt < 4; dt++) {
        int dl = wc * 64 + dt * 16 + c;
        bf16x8 vf = *(const bf16x8*)(vcur + dl * 128 +
                                     ((ks2 * 64 + g * 16) ^ ((dl & 7) << 4)));
        #pragma unroll
        for (int rt = 0; rt < 4; rt++)
          oacc[rt][dt] = __builtin_amdgcn_mfma_f32_16x16x32_bf16(pa[rt], vf,
                                                                 oacc[rt][dt], 0, 0, 0);
      }
      __builtin_amdgcn_s_setprio(0);
    }
    // end-of-tile: next buffers staged (single counted drain point per iter)
    asm volatile("s_waitcnt vmcnt(0)" ::: "memory");
    __builtin_amdgcn_sched_barrier(0);
    __builtin_amdgcn_s_barrier();
    __builtin_amdgcn_sched_barrier(0);
  }

  // write numerator partials (fp32)
  float* np = nump + (size_t)split * NROWS * DDIM;
  #pragma unroll
  for (int rt = 0; rt < 4; rt++)
    #pragma unroll
    for (int dt = 0; dt < 4; dt++)
      #pragma unroll
      for (int r = 0; r < 4; r++) {
        int rowg = q0 + wr*64 + rt*16 + g*4 + r;
        int col  = wc*64 + dt*16 + c;
        np[(size_t)rowg * DDIM + col] = oacc[rt][dt][r];
      }
  // reduce over this wave's 16 cols + write denominator partials
  #pragma unroll
  for (int rt = 0; rt < 4; rt++)
    #pragma unroll
    for (int r = 0; r < 4; r++) {
      float d = den[rt][r];
      d += __shfl_xor(d, 1); d += __shfl_xor(d, 2);
      d += __shfl_xor(d, 4); d += __shfl_xor(d, 8);
      if (c == 0)
        denp[((size_t)split * 4 + wc) * NROWS + q0 + wr*64 + rt*16 + g*4 + r] = d;
    }
}

// ---------------- kernel 3: combine partials, diagonal fix, output ----------------
__global__ __launch_bounds__(256) void combine_kernel(
    const float* __restrict__ x, const unsigned short* __restrict__ qb,
    const unsigned short* __restrict__ kb, const unsigned short* __restrict__ vb,
    const float* __restrict__ nump, const float* __restrict__ denp,
    float* __restrict__ out)
{
  const int t = threadIdx.x;
  const int w = t >> 6, l = t & 63;
  const int i = blockIdx.x * 4 + w;

  ushort4 q4 = *(const ushort4*)(qb + (size_t)i * DDIM + l * 4);
  ushort4 k4 = *(const ushort4*)(kb + (size_t)i * DDIM + l * 4);
  float s = bf2f(q4.x) * bf2f(k4.x) + bf2f(q4.y) * bf2f(k4.y)
          + bf2f(q4.z) * bf2f(k4.z) + bf2f(q4.w) * bf2f(k4.w);
  #pragma unroll
  for (int m = 1; m < 64; m <<= 1) s += __shfl_xor(s, m);
  float r  = fmaxf(s, 0.f);
  float rb = bf2f(f2bf_bits(r));   // match attn's bf16-rounded P value

  float den = 0.f;
  #pragma unroll
  for (int sp = 0; sp < KSPLIT * 4; sp++)
    den += denp[(size_t)sp * NROWS + i];
  float inv = 1.f / fmaxf(den - rb, 1e-12f);

  const int d0 = l * 4;
  float4 acc = *(const float4*)(nump + (size_t)i * DDIM + d0);
  #pragma unroll
  for (int sp = 1; sp < KSPLIT; sp++) {
    float4 a2 = *(const float4*)(nump + (size_t)sp * NROWS * DDIM + (size_t)i * DDIM + d0);
    acc.x += a2.x; acc.y += a2.y; acc.z += a2.z; acc.w += a2.w;
  }
  ushort4 v4 = *(const ushort4*)(vb + (size_t)i * DDIM + d0);
  float4 xx = *(const float4*)(x + (size_t)i * DDIM + d0);
  float4 o;
  o.x = (acc.x - rb * bf2f(v4.x)) * inv + xx.x;
  o.y = (acc.y - rb * bf2f(v4.y)) * inv + xx.y;
  o.z = (acc.z - rb * bf2f(v4.z)) * inv + xx.z;
  o.w = (acc.w - rb * bf2f(v4.w)) * inv + xx.w;
  *(float4*)(out + (size_t)i * DDIM + d0) = o;
}

extern "C" void kernel_launch(void* const* d_in, const int* in_sizes, int n_in,
                              void* d_out, int out_size, void* d_ws, size_t ws_size,
                              hipStream_t stream)
{
  const float* x  = (const float*)d_in[0];
  const float* Wq = (const float*)d_in[1];
  const float* bq = (const float*)d_in[2];
  const float* Wk = (const float*)d_in[3];
  const float* bk = (const float*)d_in[4];
  const float* Wv = (const float*)d_in[5];
  const float* bv = (const float*)d_in[6];

  char* ws = (char*)d_ws;
  unsigned short* Wb  = (unsigned short*)(ws + 0);          // 384 KB (3 matrices)
  unsigned short* qb  = (unsigned short*)(ws + 393216);     // 4 MB
  unsigned short* kb  = (unsigned short*)(ws + 4587520);    // 4 MB
  unsigned short* vb  = (unsigned short*)(ws + 8781824);    // 4 MB
  unsigned short* vT  = (unsigned short*)(ws + 12976128);   // 4 MB
  float* nump = (float*)(ws + 17170432);                    // 32 MB (4 splits)
  float* denp = (float*)(ws + 50724864);                    // 512 KB (16 slices)

  convert_kernel<<<192, 256, 0, stream>>>(Wq, Wk, Wv, Wb);
  qkv_kernel<<<384, 256, 0, stream>>>(bq, bk, bv, x, Wb, qb, kb, vb, vT);
  attn_kernel<<<(NROWS / BM) * KSPLIT, 512, 0, stream>>>(qb, kb, vT, nump, denp);
  combine_kernel<<<NROWS / 4, 256, 0, stream>>>(x, qb, kb, vb, nump, denp, (float*)d_out);
}

// Round 4
// 234.929 us; speedup vs baseline: 1.0028x; 1.0028x over previous
//
#include <hip/hip_runtime.h>

#define NROWS 8192
#define DDIM  256
#define KSPLIT 4
#define BM 128
#define BK 64
#define NT (NROWS / KSPLIT / BK)   // 32 tiles per split

typedef __bf16 bf16x8 __attribute__((ext_vector_type(8)));
typedef float  f32x4  __attribute__((ext_vector_type(4)));

typedef __attribute__((address_space(1))) unsigned int uint_gas;
typedef __attribute__((address_space(3))) unsigned int uint_las;

__device__ __forceinline__ void gload_lds16(const void* g, void* l) {
  __builtin_amdgcn_global_load_lds((const uint_gas*)g, (uint_las*)l, 16, 0, 0);
}

__device__ __forceinline__ unsigned int f2bf_bits(float f) {
  union { float f; unsigned int u; } v; v.f = f;
  unsigned int r = v.u + 0x7FFFu + ((v.u >> 16) & 1u);
  return r >> 16;
}
__device__ __forceinline__ float bf2f(unsigned int b) {
  union { unsigned int u; float f; } v; v.u = b << 16;
  return v.f;
}

// ---------------- kernel 0: fp32 -> bf16 conversion (weights only) ----------------
__global__ __launch_bounds__(256) void convert_kernel(
    const float* __restrict__ wq, const float* __restrict__ wk,
    const float* __restrict__ wv, unsigned short* __restrict__ Wb)
{
  int i = blockIdx.x * 256 + threadIdx.x;
  const int nw4 = DDIM * DDIM / 4;   // 16384
  const float4* src; int j;
  if (i < nw4)          { src = (const float4*)wq; j = i; }
  else if (i < 2*nw4)   { src = (const float4*)wk; j = i - nw4; }
  else                  { src = (const float4*)wv; j = i - 2*nw4; }
  float4 f = src[j];
  ushort4 o;
  o.x = (unsigned short)f2bf_bits(f.x);
  o.y = (unsigned short)f2bf_bits(f.y);
  o.z = (unsigned short)f2bf_bits(f.z);
  o.w = (unsigned short)f2bf_bits(f.w);
  ((ushort4*)(Wb))[i] = o;
}

// ---------------- kernel 1: QKV projections + L2 norm + vT ----------------
// grid = 384: out = bid/128 (0=q,1=k,2=v), mb = bid%128 (64-row slab)
__global__ __launch_bounds__(256) void qkv_kernel(
    const float* __restrict__ bq, const float* __restrict__ bk, const float* __restrict__ bv,
    const float* __restrict__ x, const unsigned short* __restrict__ Wb,
    unsigned short* __restrict__ qb, unsigned short* __restrict__ kb,
    unsigned short* __restrict__ vb, unsigned short* __restrict__ vT)
{
  __shared__ unsigned short vstage[DDIM * 72];
  const int t = threadIdx.x;
  const int w = t >> 6, l = t & 63;
  const int c = l & 15, g = l >> 4;
  const int out = blockIdx.x / 128;
  const int mb  = blockIdx.x % 128;
  const int row0 = mb * 64;
  const int rw = row0 + w * 16;

  // load x rows as fp32, convert to bf16 fragments in-register
  bf16x8 a[8];
  #pragma unroll
  for (int ks = 0; ks < 8; ks++) {
    const float* p = x + (size_t)(rw + c) * DDIM + ks * 32 + g * 8;
    float4 f0 = *(const float4*)p;
    float4 f1 = *(const float4*)(p + 4);
    union { bf16x8 v; unsigned short s[8]; } u;
    u.s[0] = (unsigned short)f2bf_bits(f0.x);
    u.s[1] = (unsigned short)f2bf_bits(f0.y);
    u.s[2] = (unsigned short)f2bf_bits(f0.z);
    u.s[3] = (unsigned short)f2bf_bits(f0.w);
    u.s[4] = (unsigned short)f2bf_bits(f1.x);
    u.s[5] = (unsigned short)f2bf_bits(f1.y);
    u.s[6] = (unsigned short)f2bf_bits(f1.z);
    u.s[7] = (unsigned short)f2bf_bits(f1.w);
    a[ks] = u.v;
  }

  const unsigned short* W = Wb + out * DDIM * DDIM;
  const float* bias = (out == 0) ? bq : (out == 1) ? bk : bv;
  unsigned short* dst = (out == 0) ? qb : (out == 1) ? kb : vb;
  f32x4 vals[16];
  #pragma unroll
  for (int ct = 0; ct < 16; ct++) {
    f32x4 acc = {0.f, 0.f, 0.f, 0.f};
    #pragma unroll
    for (int ks = 0; ks < 8; ks++) {
      bf16x8 b = *(const bf16x8*)(W + (size_t)(ct * 16 + c) * DDIM + ks * 32 + g * 8);
      acc = __builtin_amdgcn_mfma_f32_16x16x32_bf16(a[ks], b, acc, 0, 0, 0);
    }
    float bias_v = bias[ct * 16 + c];
    #pragma unroll
    for (int r = 0; r < 4; r++) acc[r] += bias_v;
    vals[ct] = acc;
  }
  if (out < 2) {   // L2 normalize rows (q, k)
    #pragma unroll
    for (int r = 0; r < 4; r++) {
      float ss = 0.f;
      #pragma unroll
      for (int ct = 0; ct < 16; ct++) ss += vals[ct][r] * vals[ct][r];
      ss += __shfl_xor(ss, 1); ss += __shfl_xor(ss, 2);
      ss += __shfl_xor(ss, 4); ss += __shfl_xor(ss, 8);
      float inv = 1.f / fmaxf(sqrtf(ss), 1e-12f);
      #pragma unroll
      for (int ct = 0; ct < 16; ct++) vals[ct][r] *= inv;
    }
  }
  #pragma unroll
  for (int ct = 0; ct < 16; ct++) {
    #pragma unroll
    for (int r = 0; r < 4; r++) {
      unsigned int bits = f2bf_bits(vals[ct][r]);
      unsigned int ob = (unsigned int)__shfl_xor((int)bits, 1);
      if (!(l & 1))
        *(unsigned int*)(dst + (size_t)(rw + g * 4 + r) * DDIM + ct * 16 + c) =
            bits | (ob << 16);
      if (out == 2)
        vstage[(ct * 16 + c) * 72 + (w * 16 + g * 4 + r)] = (unsigned short)bits;
    }
  }
  if (out == 2) {
    __syncthreads();
    #pragma unroll
    for (int p = 0; p < 8; p++) {
      int dd = (t >> 3) + p * 32;
      int ch = t & 7;
      *(uint4*)(vT + (size_t)dd * NROWS + row0 + ch * 8) =
          *(const uint4*)(vstage + dd * 72 + ch * 8);
    }
  }
}

// ---------------- kernel 2: fused relu-attention partials ----------------
// BM=128 q-rows/block, 8 waves as 2 row-groups x 4 col-groups.
// Per-wave S tile = 64 rows x 16 cols; PV tile = 64 rows x 64 d-cols.
// launch_bounds(512,1): ~245 VGPR demand needs the 256 cap — (512,2) spilled (R3).
__global__ __launch_bounds__(512, 1) void attn_kernel(
    const unsigned short* __restrict__ qb, const unsigned short* __restrict__ kb,
    const unsigned short* __restrict__ vT,
    float* __restrict__ nump, float* __restrict__ denp)
{
  // 2x32KB K dbuf | 2x32KB vT dbuf | 16KB P ([128][64] bf16, XOR-swizzled)
  __shared__ __align__(16) char smem[147456];
  char* kbuf = smem;
  char* vbuf = smem + 65536;
  char* P    = smem + 131072;

  const int t = threadIdx.x;
  const int w = t >> 6, l = t & 63;
  const int c = l & 15, g = l >> 4;
  const int wr = w >> 2, wc = w & 3;   // wr 0..1 (64 rows), wc 0..3 (16 S-cols / 64 d-cols)
  const int bid = blockIdx.x;
  const int split = bid & (KSPLIT - 1);
  const int mb = bid >> 2;
  const int q0 = mb * BM;
  const int kbase0 = split * (NROWS / KSPLIT);

  const char* kbc = (const char*)kb;
  const char* vtc = (const char*)vT;

  // hoist q fragments: 4 row-tiles x 8 k-steps = 128 VGPR
  bf16x8 qa[4][8];
  #pragma unroll
  for (int rt = 0; rt < 4; rt++)
    #pragma unroll
    for (int ks = 0; ks < 8; ks++)
      qa[rt][ks] = *(const bf16x8*)(qb + (size_t)(q0 + wr*64 + rt*16 + c) * DDIM + ks*32 + g*8);

  f32x4 oacc[4][4];
  #pragma unroll
  for (int rt = 0; rt < 4; rt++)
    #pragma unroll
    for (int dt = 0; dt < 4; dt++)
      oacc[rt][dt] = (f32x4){0.f, 0.f, 0.f, 0.f};
  float den[4][4];
  #pragma unroll
  for (int rt = 0; rt < 4; rt++)
    #pragma unroll
    for (int r = 0; r < 4; r++) den[rt][r] = 0.f;

  auto stage = [&](int buf, int it) {
    const int kbase = kbase0 + it * BK;
    const char* ksrc = kbc + (size_t)kbase * 512;
    #pragma unroll
    for (int i = 0; i < 4; i++) {
      int n = i * 512 + t;
      int row = n >> 5, slot = n & 31;
      gload_lds16(ksrc + row * 512 + ((slot ^ (row & 7)) * 16),
                  kbuf + buf * 32768 + i * 8192 + w * 1024);
    }
    const char* vsrc = vtc + (size_t)kbase * 2;
    #pragma unroll
    for (int i = 0; i < 4; i++) {
      int n = i * 512 + t;
      int dd = n >> 3, slot = n & 7;
      gload_lds16(vsrc + (size_t)dd * (NROWS * 2) + ((slot ^ (dd & 7)) * 16),
                  vbuf + buf * 32768 + i * 8192 + w * 1024);
    }
  };

  // prologue: stage tile 0 into buf 0
  stage(0, 0);
  asm volatile("s_waitcnt vmcnt(0)" ::: "memory");
  __builtin_amdgcn_sched_barrier(0);
  __builtin_amdgcn_s_barrier();
  __builtin_amdgcn_sched_barrier(0);

  for (int it = 0; it < NT; ++it) {
    const int cur = it & 1;
    if (it + 1 < NT) stage(cur ^ 1, it + 1);
    __builtin_amdgcn_sched_barrier(0);

    // ---- QK^T: this wave's 64 rows x 16 cols ----
    const char* kcur = kbuf + cur * 32768;
    f32x4 sacc[4];
    #pragma unroll
    for (int rt = 0; rt < 4; rt++) sacc[rt] = (f32x4){0.f, 0.f, 0.f, 0.f};
    const int rl = wc * 16 + c;
    __builtin_amdgcn_s_setprio(1);
    #pragma unroll
    for (int ks = 0; ks < 8; ks++) {
      bf16x8 kf = *(const bf16x8*)(kcur + rl * 512 + ((ks * 64 + g * 16) ^ ((rl & 7) << 4)));
      #pragma unroll
      for (int rt = 0; rt < 4; rt++)
        sacc[rt] = __builtin_amdgcn_mfma_f32_16x16x32_bf16(qa[rt][ks], kf, sacc[rt], 0, 0, 0);
    }
    __builtin_amdgcn_s_setprio(0);

    // relu, denominator accumulate, pack P to LDS (swizzled [128][64] bf16)
    #pragma unroll
    for (int rt = 0; rt < 4; rt++)
      #pragma unroll
      for (int r = 0; r < 4; r++) {
        float v = fmaxf(sacc[rt][r], 0.f);
        den[rt][r] += v;
        unsigned int bits = f2bf_bits(v);
        unsigned int ob = (unsigned int)__shfl_xor((int)bits, 1);
        if (!(l & 1)) {
          int prow = wr * 64 + rt * 16 + g * 4 + r;
          int pcol = wc * 16 + c;   // even
          *(unsigned int*)(P + prow * 128 + ((pcol * 2) ^ ((prow & 7) << 4))) =
              bits | (ob << 16);
        }
      }
    // P visibility barrier — LDS-only drain, prefetch loads stay in flight
    asm volatile("s_waitcnt lgkmcnt(0)" ::: "memory");
    __builtin_amdgcn_sched_barrier(0);
    __builtin_amdgcn_s_barrier();
    __builtin_amdgcn_sched_barrier(0);

    // ---- PV: this wave's 64 rows x 64 d-cols ----
    const char* vcur = vbuf + cur * 32768;
    #pragma unroll
    for (int ks2 = 0; ks2 < 2; ks2++) {
      bf16x8 pa[4];
      #pragma unroll
      for (int rt = 0; rt < 4; rt++) {
        int prow = wr * 64 + rt * 16 + c;
        pa[rt] = *(const bf16x8*)(P + prow * 128 +
                                  ((ks2 * 64 + g * 16) ^ ((prow & 7) << 4)));
      }
      __builtin_amdgcn_s_setprio(1);
      #pragma unroll
      for (int dt = 0; dt < 4; dt++) {
        int dl = wc * 64 + dt * 16 + c;
        bf16x8 vf = *(const bf16x8*)(vcur + dl * 128 +
                                     ((ks2 * 64 + g * 16) ^ ((dl & 7) << 4)));
        #pragma unroll
        for (int rt = 0; rt < 4; rt++)
          oacc[rt][dt] = __builtin_amdgcn_mfma_f32_16x16x32_bf16(pa[rt], vf,
                                                                 oacc[rt][dt], 0, 0, 0);
      }
      __builtin_amdgcn_s_setprio(0);
    }
    // end-of-tile: next buffers staged (single counted drain point per iter)
    asm volatile("s_waitcnt vmcnt(0)" ::: "memory");
    __builtin_amdgcn_sched_barrier(0);
    __builtin_amdgcn_s_barrier();
    __builtin_amdgcn_sched_barrier(0);
  }

  // write numerator partials (fp32)
  float* np = nump + (size_t)split * NROWS * DDIM;
  #pragma unroll
  for (int rt = 0; rt < 4; rt++)
    #pragma unroll
    for (int dt = 0; dt < 4; dt++)
      #pragma unroll
      for (int r = 0; r < 4; r++) {
        int rowg = q0 + wr*64 + rt*16 + g*4 + r;
        int col  = wc*64 + dt*16 + c;
        np[(size_t)rowg * DDIM + col] = oacc[rt][dt][r];
      }
  // reduce over this wave's 16 cols + write denominator partials
  #pragma unroll
  for (int rt = 0; rt < 4; rt++)
    #pragma unroll
    for (int r = 0; r < 4; r++) {
      float d = den[rt][r];
      d += __shfl_xor(d, 1); d += __shfl_xor(d, 2);
      d += __shfl_xor(d, 4); d += __shfl_xor(d, 8);
      if (c == 0)
        denp[((size_t)split * 4 + wc) * NROWS + q0 + wr*64 + rt*16 + g*4 + r] = d;
    }
}

// ---------------- kernel 3: combine partials, diagonal fix, output ----------------
__global__ __launch_bounds__(256) void combine_kernel(
    const float* __restrict__ x, const unsigned short* __restrict__ qb,
    const unsigned short* __restrict__ kb, const unsigned short* __restrict__ vb,
    const float* __restrict__ nump, const float* __restrict__ denp,
    float* __restrict__ out)
{
  const int t = threadIdx.x;
  const int w = t >> 6, l = t & 63;
  const int i = blockIdx.x * 4 + w;

  ushort4 q4 = *(const ushort4*)(qb + (size_t)i * DDIM + l * 4);
  ushort4 k4 = *(const ushort4*)(kb + (size_t)i * DDIM + l * 4);
  float s = bf2f(q4.x) * bf2f(k4.x) + bf2f(q4.y) * bf2f(k4.y)
          + bf2f(q4.z) * bf2f(k4.z) + bf2f(q4.w) * bf2f(k4.w);
  #pragma unroll
  for (int m = 1; m < 64; m <<= 1) s += __shfl_xor(s, m);
  float r  = fmaxf(s, 0.f);
  float rb = bf2f(f2bf_bits(r));   // match attn's bf16-rounded P value

  float den = 0.f;
  #pragma unroll
  for (int sp = 0; sp < KSPLIT * 4; sp++)
    den += denp[(size_t)sp * NROWS + i];
  float inv = 1.f / fmaxf(den - rb, 1e-12f);

  const int d0 = l * 4;
  float4 acc = *(const float4*)(nump + (size_t)i * DDIM + d0);
  #pragma unroll
  for (int sp = 1; sp < KSPLIT; sp++) {
    float4 a2 = *(const float4*)(nump + (size_t)sp * NROWS * DDIM + (size_t)i * DDIM + d0);
    acc.x += a2.x; acc.y += a2.y; acc.z += a2.z; acc.w += a2.w;
  }
  ushort4 v4 = *(const ushort4*)(vb + (size_t)i * DDIM + d0);
  float4 xx = *(const float4*)(x + (size_t)i * DDIM + d0);
  float4 o;
  o.x = (acc.x - rb * bf2f(v4.x)) * inv + xx.x;
  o.y = (acc.y - rb * bf2f(v4.y)) * inv + xx.y;
  o.z = (acc.z - rb * bf2f(v4.z)) * inv + xx.z;
  o.w = (acc.w - rb * bf2f(v4.w)) * inv + xx.w;
  *(float4*)(out + (size_t)i * DDIM + d0) = o;
}

extern "C" void kernel_launch(void* const* d_in, const int* in_sizes, int n_in,
                              void* d_out, int out_size, void* d_ws, size_t ws_size,
                              hipStream_t stream)
{
  const float* x  = (const float*)d_in[0];
  const float* Wq = (const float*)d_in[1];
  const float* bq = (const float*)d_in[2];
  const float* Wk = (const float*)d_in[3];
  const float* bk = (const float*)d_in[4];
  const float* Wv = (const float*)d_in[5];
  const float* bv = (const float*)d_in[6];

  char* ws = (char*)d_ws;
  unsigned short* Wb  = (unsigned short*)(ws + 0);          // 384 KB (3 matrices)
  unsigned short* qb  = (unsigned short*)(ws + 393216);     // 4 MB
  unsigned short* kb  = (unsigned short*)(ws + 4587520);    // 4 MB
  unsigned short* vb  = (unsigned short*)(ws + 8781824);    // 4 MB
  unsigned short* vT  = (unsigned short*)(ws + 12976128);   // 4 MB
  float* nump = (float*)(ws + 17170432);                    // 32 MB (4 splits)
  float* denp = (float*)(ws + 50724864);                    // 512 KB (16 slices)

  convert_kernel<<<192, 256, 0, stream>>>(Wq, Wk, Wv, Wb);
  qkv_kernel<<<384, 256, 0, stream>>>(bq, bk, bv, x, Wb, qb, kb, vb, vT);
  attn_kernel<<<(NROWS / BM) * KSPLIT, 512, 0, stream>>>(qb, kb, vT, nump, denp);
  combine_kernel<<<NROWS / 4, 256, 0, stream>>>(x, qb, kb, vb, nump, denp, (float*)d_out);
}

// Round 5
// 132.280 us; speedup vs baseline: 1.7810x; 1.7760x over previous
//
#include <hip/hip_runtime.h>

#define NROWS 8192
#define DDIM  256
#define KSPLIT 4
#define BM 128
#define BK 64
#define NT (NROWS / KSPLIT / BK)   // 32 tiles per split

typedef __bf16 bf16x8 __attribute__((ext_vector_type(8)));
typedef float  f32x4  __attribute__((ext_vector_type(4)));

typedef __attribute__((address_space(1))) unsigned int uint_gas;
typedef __attribute__((address_space(3))) unsigned int uint_las;

__device__ __forceinline__ void gload_lds16(const void* g, void* l) {
  __builtin_amdgcn_global_load_lds((const uint_gas*)g, (uint_las*)l, 16, 0, 0);
}

__device__ __forceinline__ unsigned int f2bf_bits(float f) {
  union { float f; unsigned int u; } v; v.f = f;
  unsigned int r = v.u + 0x7FFFu + ((v.u >> 16) & 1u);
  return r >> 16;
}
__device__ __forceinline__ float bf2f(unsigned int b) {
  union { unsigned int u; float f; } v; v.u = b << 16;
  return v.f;
}
// pack two f32 -> one u32 of 2x bf16 (RNE); compiler emits v_cvt_pk_bf16_f32
__device__ __forceinline__ unsigned int pack2bf(float a, float b) {
  union { unsigned int u; __bf16 h[2]; } p;
  p.h[0] = (__bf16)a; p.h[1] = (__bf16)b;
  return p.u;
}

// ---------------- kernel 0: fp32 -> bf16 conversion (weights only) ----------------
__global__ __launch_bounds__(256) void convert_kernel(
    const float* __restrict__ wq, const float* __restrict__ wk,
    const float* __restrict__ wv, unsigned short* __restrict__ Wb)
{
  int i = blockIdx.x * 256 + threadIdx.x;
  const int nw4 = DDIM * DDIM / 4;   // 16384
  const float4* src; int j;
  if (i < nw4)          { src = (const float4*)wq; j = i; }
  else if (i < 2*nw4)   { src = (const float4*)wk; j = i - nw4; }
  else                  { src = (const float4*)wv; j = i - 2*nw4; }
  float4 f = src[j];
  ushort4 o;
  o.x = (unsigned short)f2bf_bits(f.x);
  o.y = (unsigned short)f2bf_bits(f.y);
  o.z = (unsigned short)f2bf_bits(f.z);
  o.w = (unsigned short)f2bf_bits(f.w);
  ((ushort4*)(Wb))[i] = o;
}

// ---------------- kernel 1: QKV projections + L2 norm + vT ----------------
// grid = 384: out = bid/128 (0=q,1=k,2=v), mb = bid%128 (64-row slab)
__global__ __launch_bounds__(256) void qkv_kernel(
    const float* __restrict__ bq, const float* __restrict__ bk, const float* __restrict__ bv,
    const float* __restrict__ x, const unsigned short* __restrict__ Wb,
    unsigned short* __restrict__ qb, unsigned short* __restrict__ kb,
    unsigned short* __restrict__ vb, unsigned short* __restrict__ vT)
{
  __shared__ unsigned short vstage[DDIM * 72];
  const int t = threadIdx.x;
  const int w = t >> 6, l = t & 63;
  const int c = l & 15, g = l >> 4;
  const int out = blockIdx.x / 128;
  const int mb  = blockIdx.x % 128;
  const int row0 = mb * 64;
  const int rw = row0 + w * 16;

  // load x rows as fp32, convert to bf16 fragments in-register
  bf16x8 a[8];
  #pragma unroll
  for (int ks = 0; ks < 8; ks++) {
    const float* p = x + (size_t)(rw + c) * DDIM + ks * 32 + g * 8;
    float4 f0 = *(const float4*)p;
    float4 f1 = *(const float4*)(p + 4);
    union { bf16x8 v; unsigned short s[8]; } u;
    u.s[0] = (unsigned short)f2bf_bits(f0.x);
    u.s[1] = (unsigned short)f2bf_bits(f0.y);
    u.s[2] = (unsigned short)f2bf_bits(f0.z);
    u.s[3] = (unsigned short)f2bf_bits(f0.w);
    u.s[4] = (unsigned short)f2bf_bits(f1.x);
    u.s[5] = (unsigned short)f2bf_bits(f1.y);
    u.s[6] = (unsigned short)f2bf_bits(f1.z);
    u.s[7] = (unsigned short)f2bf_bits(f1.w);
    a[ks] = u.v;
  }

  const unsigned short* W = Wb + out * DDIM * DDIM;
  const float* bias = (out == 0) ? bq : (out == 1) ? bk : bv;
  unsigned short* dst = (out == 0) ? qb : (out == 1) ? kb : vb;
  f32x4 vals[16];
  #pragma unroll
  for (int ct = 0; ct < 16; ct++) {
    f32x4 acc = {0.f, 0.f, 0.f, 0.f};
    #pragma unroll
    for (int ks = 0; ks < 8; ks++) {
      bf16x8 b = *(const bf16x8*)(W + (size_t)(ct * 16 + c) * DDIM + ks * 32 + g * 8);
      acc = __builtin_amdgcn_mfma_f32_16x16x32_bf16(a[ks], b, acc, 0, 0, 0);
    }
    float bias_v = bias[ct * 16 + c];
    #pragma unroll
    for (int r = 0; r < 4; r++) acc[r] += bias_v;
    vals[ct] = acc;
  }
  if (out < 2) {   // L2 normalize rows (q, k)
    #pragma unroll
    for (int r = 0; r < 4; r++) {
      float ss = 0.f;
      #pragma unroll
      for (int ct = 0; ct < 16; ct++) ss += vals[ct][r] * vals[ct][r];
      ss += __shfl_xor(ss, 1); ss += __shfl_xor(ss, 2);
      ss += __shfl_xor(ss, 4); ss += __shfl_xor(ss, 8);
      float inv = 1.f / fmaxf(sqrtf(ss), 1e-12f);
      #pragma unroll
      for (int ct = 0; ct < 16; ct++) vals[ct][r] *= inv;
    }
  }
  #pragma unroll
  for (int ct = 0; ct < 16; ct++) {
    #pragma unroll
    for (int r = 0; r < 4; r++) {
      unsigned int bits = f2bf_bits(vals[ct][r]);
      unsigned int ob = (unsigned int)__shfl_xor((int)bits, 1);
      if (!(l & 1))
        *(unsigned int*)(dst + (size_t)(rw + g * 4 + r) * DDIM + ct * 16 + c) =
            bits | (ob << 16);
      if (out == 2)
        vstage[(ct * 16 + c) * 72 + (w * 16 + g * 4 + r)] = (unsigned short)bits;
    }
  }
  if (out == 2) {
    __syncthreads();
    #pragma unroll
    for (int p = 0; p < 8; p++) {
      int dd = (t >> 3) + p * 32;
      int ch = t & 7;
      *(uint4*)(vT + (size_t)dd * NROWS + row0 + ch * 8) =
          *(const uint4*)(vstage + dd * 72 + ch * 8);
    }
  }
}

// ---------------- kernel 2: fused relu-attention partials ----------------
// BM=128, 8 waves as 4 row-groups x 2 col-groups (R2's no-spill shape).
// QK^T computed SWAPPED: mfma(K,Q) -> S^T, so each lane holds 4 consecutive
// k-cols of one q-row -> in-lane cvt_pk + ds_write_b64 pack (no shfl, no
// divergence), and den is a pure per-lane accumulator reduced after the loop.
__global__ __launch_bounds__(512, 2) void attn_kernel(
    const unsigned short* __restrict__ qb, const unsigned short* __restrict__ kb,
    const unsigned short* __restrict__ vT,
    float* __restrict__ nump, float* __restrict__ denp)
{
  // 2x32KB K dbuf | 2x32KB vT dbuf | 16KB P ([128][64] bf16, XOR-swizzled)
  __shared__ __align__(16) char smem[147456];
  char* kbuf = smem;
  char* vbuf = smem + 65536;
  char* P    = smem + 131072;

  const int t = threadIdx.x;
  const int w = t >> 6, l = t & 63;
  const int c = l & 15, g = l >> 4;
  const int wr = w >> 1, wc = w & 1;   // wr 0..3 (32 rows each), wc 0..1
  const int bid = blockIdx.x;
  const int split = bid & (KSPLIT - 1);
  const int mb = bid >> 2;
  const int q0 = mb * BM;
  const int kbase0 = split * (NROWS / KSPLIT);

  const char* kbc = (const char*)kb;
  const char* vtc = (const char*)vT;

  // hoist q fragments: 2 row-tiles x 8 k-steps = 64 VGPR
  bf16x8 qa[2][8];
  #pragma unroll
  for (int rt = 0; rt < 2; rt++)
    #pragma unroll
    for (int ks = 0; ks < 8; ks++)
      qa[rt][ks] = *(const bf16x8*)(qb + (size_t)(q0 + wr*32 + rt*16 + c) * DDIM + ks*32 + g*8);

  f32x4 oacc[2][8];
  #pragma unroll
  for (int rt = 0; rt < 2; rt++)
    #pragma unroll
    for (int dt = 0; dt < 8; dt++)
      oacc[rt][dt] = (f32x4){0.f, 0.f, 0.f, 0.f};
  float denl[2] = {0.f, 0.f};   // per-lane partial row-sums (rt-indexed)

  auto stage = [&](int buf, int it) {
    const int kbase = kbase0 + it * BK;
    const char* ksrc = kbc + (size_t)kbase * 512;
    #pragma unroll
    for (int i = 0; i < 4; i++) {
      int n = i * 512 + t;
      int row = n >> 5, slot = n & 31;
      gload_lds16(ksrc + row * 512 + ((slot ^ (row & 7)) * 16),
                  kbuf + buf * 32768 + i * 8192 + w * 1024);
    }
    const char* vsrc = vtc + (size_t)kbase * 2;
    #pragma unroll
    for (int i = 0; i < 4; i++) {
      int n = i * 512 + t;
      int dd = n >> 3, slot = n & 7;
      gload_lds16(vsrc + (size_t)dd * (NROWS * 2) + ((slot ^ (dd & 7)) * 16),
                  vbuf + buf * 32768 + i * 8192 + w * 1024);
    }
  };

  // prologue: stage tile 0 into buf 0
  stage(0, 0);
  asm volatile("s_waitcnt vmcnt(0)" ::: "memory");
  __builtin_amdgcn_sched_barrier(0);
  __builtin_amdgcn_s_barrier();
  __builtin_amdgcn_sched_barrier(0);

  for (int it = 0; it < NT; ++it) {
    const int cur = it & 1;
    if (it + 1 < NT) stage(cur ^ 1, it + 1);
    __builtin_amdgcn_sched_barrier(0);

    // ---- QK^T (swapped): S^T[k-col][q-row] for 32 cols x 32 rows ----
    const char* kcur = kbuf + cur * 32768;
    f32x4 sacc[2][2];   // [kt][rt]
    #pragma unroll
    for (int kt = 0; kt < 2; kt++)
      #pragma unroll
      for (int rt = 0; rt < 2; rt++)
        sacc[kt][rt] = (f32x4){0.f, 0.f, 0.f, 0.f};
    #pragma unroll
    for (int ks = 0; ks < 8; ks++) {
      bf16x8 kf[2];
      #pragma unroll
      for (int kt = 0; kt < 2; kt++) {
        int rl = wc * 32 + kt * 16 + c;
        kf[kt] = *(const bf16x8*)(kcur + rl * 512 + ((ks * 64 + g * 16) ^ ((rl & 7) << 4)));
      }
      #pragma unroll
      for (int kt = 0; kt < 2; kt++)
        #pragma unroll
        for (int rt = 0; rt < 2; rt++)
          sacc[kt][rt] = __builtin_amdgcn_mfma_f32_16x16x32_bf16(kf[kt], qa[rt][ks],
                                                                 sacc[kt][rt], 0, 0, 0);
    }
    // relu + in-lane bf16 pack + b64 store; den accumulates per-lane
    #pragma unroll
    for (int kt = 0; kt < 2; kt++)
      #pragma unroll
      for (int rt = 0; rt < 2; rt++) {
        float v0 = fmaxf(sacc[kt][rt][0], 0.f);
        float v1 = fmaxf(sacc[kt][rt][1], 0.f);
        float v2 = fmaxf(sacc[kt][rt][2], 0.f);
        float v3 = fmaxf(sacc[kt][rt][3], 0.f);
        denl[rt] += (v0 + v1) + (v2 + v3);
        uint2 d2;
        d2.x = pack2bf(v0, v1);
        d2.y = pack2bf(v2, v3);
        int prow = wr * 32 + rt * 16 + c;          // q-row
        int pcol = wc * 32 + kt * 16 + g * 4;      // k-col base (4 wide)
        *(uint2*)(P + prow * 128 + ((pcol * 2) ^ ((prow & 7) << 4))) = d2;
      }
    // P visibility barrier — LDS-only drain, prefetch loads stay in flight
    asm volatile("s_waitcnt lgkmcnt(0)" ::: "memory");
    __builtin_amdgcn_sched_barrier(0);
    __builtin_amdgcn_s_barrier();
    __builtin_amdgcn_sched_barrier(0);

    // ---- PV: this wave's 32 rows x 128 d-cols ----
    const char* vcur = vbuf + cur * 32768;
    #pragma unroll
    for (int ks2 = 0; ks2 < 2; ks2++) {
      bf16x8 pa[2];
      #pragma unroll
      for (int rt = 0; rt < 2; rt++) {
        int prow = wr * 32 + rt * 16 + c;
        pa[rt] = *(const bf16x8*)(P + prow * 128 +
                                  ((ks2 * 64 + g * 16) ^ ((prow & 7) << 4)));
      }
      #pragma unroll
      for (int dt = 0; dt < 8; dt++) {
        int dl = wc * 128 + dt * 16 + c;
        bf16x8 vf = *(const bf16x8*)(vcur + dl * 128 +
                                     ((ks2 * 64 + g * 16) ^ ((dl & 7) << 4)));
        #pragma unroll
        for (int rt = 0; rt < 2; rt++)
          oacc[rt][dt] = __builtin_amdgcn_mfma_f32_16x16x32_bf16(pa[rt], vf,
                                                                 oacc[rt][dt], 0, 0, 0);
      }
    }
    // end-of-tile: next buffers staged (prefetch had the whole iter in flight)
    asm volatile("s_waitcnt vmcnt(0)" ::: "memory");
    __builtin_amdgcn_sched_barrier(0);
    __builtin_amdgcn_s_barrier();
    __builtin_amdgcn_sched_barrier(0);
  }

  // write numerator partials (fp32)
  float* np = nump + (size_t)split * NROWS * DDIM;
  #pragma unroll
  for (int rt = 0; rt < 2; rt++)
    #pragma unroll
    for (int dt = 0; dt < 8; dt++)
      #pragma unroll
      for (int r = 0; r < 4; r++) {
        int rowg = q0 + wr*32 + rt*16 + g*4 + r;
        int col  = wc*128 + dt*16 + c;
        np[(size_t)rowg * DDIM + col] = oacc[rt][dt][r];
      }
  // reduce per-lane den over g-groups (lanes ^16, ^32) and write partials
  #pragma unroll
  for (int rt = 0; rt < 2; rt++) {
    float d = denl[rt];
    d += __shfl_xor(d, 16);
    d += __shfl_xor(d, 32);
    if (l < 16)
      denp[((size_t)split * 2 + wc) * NROWS + q0 + wr*32 + rt*16 + l] = d;
  }
}

// ---------------- kernel 3: combine partials, diagonal fix, output ----------------
__global__ __launch_bounds__(256) void combine_kernel(
    const float* __restrict__ x, const unsigned short* __restrict__ qb,
    const unsigned short* __restrict__ kb, const unsigned short* __restrict__ vb,
    const float* __restrict__ nump, const float* __restrict__ denp,
    float* __restrict__ out)
{
  const int t = threadIdx.x;
  const int w = t >> 6, l = t & 63;
  const int i = blockIdx.x * 4 + w;

  ushort4 q4 = *(const ushort4*)(qb + (size_t)i * DDIM + l * 4);
  ushort4 k4 = *(const ushort4*)(kb + (size_t)i * DDIM + l * 4);
  float s = bf2f(q4.x) * bf2f(k4.x) + bf2f(q4.y) * bf2f(k4.y)
          + bf2f(q4.z) * bf2f(k4.z) + bf2f(q4.w) * bf2f(k4.w);
  #pragma unroll
  for (int m = 1; m < 64; m <<= 1) s += __shfl_xor(s, m);
  float r  = fmaxf(s, 0.f);
  float rb = bf2f(f2bf_bits(r));   // match attn's bf16-rounded P value

  float den = 0.f;
  #pragma unroll
  for (int sp = 0; sp < KSPLIT * 2; sp++)
    den += denp[(size_t)sp * NROWS + i];
  float inv = 1.f / fmaxf(den - rb, 1e-12f);

  const int d0 = l * 4;
  float4 acc = *(const float4*)(nump + (size_t)i * DDIM + d0);
  #pragma unroll
  for (int sp = 1; sp < KSPLIT; sp++) {
    float4 a2 = *(const float4*)(nump + (size_t)sp * NROWS * DDIM + (size_t)i * DDIM + d0);
    acc.x += a2.x; acc.y += a2.y; acc.z += a2.z; acc.w += a2.w;
  }
  ushort4 v4 = *(const ushort4*)(vb + (size_t)i * DDIM + d0);
  float4 xx = *(const float4*)(x + (size_t)i * DDIM + d0);
  float4 o;
  o.x = (acc.x - rb * bf2f(v4.x)) * inv + xx.x;
  o.y = (acc.y - rb * bf2f(v4.y)) * inv + xx.y;
  o.z = (acc.z - rb * bf2f(v4.z)) * inv + xx.z;
  o.w = (acc.w - rb * bf2f(v4.w)) * inv + xx.w;
  *(float4*)(out + (size_t)i * DDIM + d0) = o;
}

extern "C" void kernel_launch(void* const* d_in, const int* in_sizes, int n_in,
                              void* d_out, int out_size, void* d_ws, size_t ws_size,
                              hipStream_t stream)
{
  const float* x  = (const float*)d_in[0];
  const float* Wq = (const float*)d_in[1];
  const float* bq = (const float*)d_in[2];
  const float* Wk = (const float*)d_in[3];
  const float* bk = (const float*)d_in[4];
  const float* Wv = (const float*)d_in[5];
  const float* bv = (const float*)d_in[6];

  char* ws = (char*)d_ws;
  unsigned short* Wb  = (unsigned short*)(ws + 0);          // 384 KB (3 matrices)
  unsigned short* qb  = (unsigned short*)(ws + 393216);     // 4 MB
  unsigned short* kb  = (unsigned short*)(ws + 4587520);    // 4 MB
  unsigned short* vb  = (unsigned short*)(ws + 8781824);    // 4 MB
  unsigned short* vT  = (unsigned short*)(ws + 12976128);   // 4 MB
  float* nump = (float*)(ws + 17170432);                    // 32 MB (4 splits)
  float* denp = (float*)(ws + 50724864);                    // 256 KB (8 slices)

  convert_kernel<<<192, 256, 0, stream>>>(Wq, Wk, Wv, Wb);
  qkv_kernel<<<384, 256, 0, stream>>>(bq, bk, bv, x, Wb, qb, kb, vb, vT);
  attn_kernel<<<(NROWS / BM) * KSPLIT, 512, 0, stream>>>(qb, kb, vT, nump, denp);
  combine_kernel<<<NROWS / 4, 256, 0, stream>>>(x, qb, kb, vb, nump, denp, (float*)d_out);
}

// Round 6
// 132.054 us; speedup vs baseline: 1.7841x; 1.0017x over previous
//
#include <hip/hip_runtime.h>

#define NROWS 8192
#define DDIM  256
#define KSPLIT 4
#define BM 128
#define BK 64
#define NT (NROWS / KSPLIT / BK)   // 32 tiles per split

typedef __bf16 bf16x8 __attribute__((ext_vector_type(8)));
typedef float  f32x4  __attribute__((ext_vector_type(4)));
typedef float  f32x16 __attribute__((ext_vector_type(16)));

typedef __attribute__((address_space(1))) unsigned int uint_gas;
typedef __attribute__((address_space(3))) unsigned int uint_las;

__device__ __forceinline__ void gload_lds16(const void* g, void* l) {
  __builtin_amdgcn_global_load_lds((const uint_gas*)g, (uint_las*)l, 16, 0, 0);
}

__device__ __forceinline__ unsigned int f2bf_bits(float f) {
  union { float f; unsigned int u; } v; v.f = f;
  unsigned int r = v.u + 0x7FFFu + ((v.u >> 16) & 1u);
  return r >> 16;
}
__device__ __forceinline__ float bf2f(unsigned int b) {
  union { unsigned int u; float f; } v; v.u = b << 16;
  return v.f;
}
// pack two f32 -> one u32 of 2x bf16 (RNE); compiler emits v_cvt_pk_bf16_f32
__device__ __forceinline__ unsigned int pack2bf(float a, float b) {
  union { unsigned int u; __bf16 h[2]; } p;
  p.h[0] = (__bf16)a; p.h[1] = (__bf16)b;
  return p.u;
}

// ---------------- kernel 0: fp32 -> bf16 conversion (weights only) ----------------
__global__ __launch_bounds__(256) void convert_kernel(
    const float* __restrict__ wq, const float* __restrict__ wk,
    const float* __restrict__ wv, unsigned short* __restrict__ Wb)
{
  int i = blockIdx.x * 256 + threadIdx.x;
  const int nw4 = DDIM * DDIM / 4;   // 16384
  const float4* src; int j;
  if (i < nw4)          { src = (const float4*)wq; j = i; }
  else if (i < 2*nw4)   { src = (const float4*)wk; j = i - nw4; }
  else                  { src = (const float4*)wv; j = i - 2*nw4; }
  float4 f = src[j];
  ushort4 o;
  o.x = (unsigned short)f2bf_bits(f.x);
  o.y = (unsigned short)f2bf_bits(f.y);
  o.z = (unsigned short)f2bf_bits(f.z);
  o.w = (unsigned short)f2bf_bits(f.w);
  ((ushort4*)(Wb))[i] = o;
}

// ---------------- kernel 1: QKV projections + L2 norm + vT ----------------
// grid = 384: out = bid/128 (0=q,1=k,2=v), mb = bid%128 (64-row slab)
__global__ __launch_bounds__(256) void qkv_kernel(
    const float* __restrict__ bq, const float* __restrict__ bk, const float* __restrict__ bv,
    const float* __restrict__ x, const unsigned short* __restrict__ Wb,
    unsigned short* __restrict__ qb, unsigned short* __restrict__ kb,
    unsigned short* __restrict__ vb, unsigned short* __restrict__ vT)
{
  __shared__ unsigned short vstage[DDIM * 72];
  const int t = threadIdx.x;
  const int w = t >> 6, l = t & 63;
  const int c = l & 15, g = l >> 4;
  const int out = blockIdx.x / 128;
  const int mb  = blockIdx.x % 128;
  const int row0 = mb * 64;
  const int rw = row0 + w * 16;

  // load x rows as fp32, convert to bf16 fragments in-register
  bf16x8 a[8];
  #pragma unroll
  for (int ks = 0; ks < 8; ks++) {
    const float* p = x + (size_t)(rw + c) * DDIM + ks * 32 + g * 8;
    float4 f0 = *(const float4*)p;
    float4 f1 = *(const float4*)(p + 4);
    union { bf16x8 v; unsigned short s[8]; } u;
    u.s[0] = (unsigned short)f2bf_bits(f0.x);
    u.s[1] = (unsigned short)f2bf_bits(f0.y);
    u.s[2] = (unsigned short)f2bf_bits(f0.z);
    u.s[3] = (unsigned short)f2bf_bits(f0.w);
    u.s[4] = (unsigned short)f2bf_bits(f1.x);
    u.s[5] = (unsigned short)f2bf_bits(f1.y);
    u.s[6] = (unsigned short)f2bf_bits(f1.z);
    u.s[7] = (unsigned short)f2bf_bits(f1.w);
    a[ks] = u.v;
  }

  const unsigned short* W = Wb + out * DDIM * DDIM;
  const float* bias = (out == 0) ? bq : (out == 1) ? bk : bv;
  unsigned short* dst = (out == 0) ? qb : (out == 1) ? kb : vb;
  f32x4 vals[16];
  #pragma unroll
  for (int ct = 0; ct < 16; ct++) {
    f32x4 acc = {0.f, 0.f, 0.f, 0.f};
    #pragma unroll
    for (int ks = 0; ks < 8; ks++) {
      bf16x8 b = *(const bf16x8*)(W + (size_t)(ct * 16 + c) * DDIM + ks * 32 + g * 8);
      acc = __builtin_amdgcn_mfma_f32_16x16x32_bf16(a[ks], b, acc, 0, 0, 0);
    }
    float bias_v = bias[ct * 16 + c];
    #pragma unroll
    for (int r = 0; r < 4; r++) acc[r] += bias_v;
    vals[ct] = acc;
  }
  if (out < 2) {   // L2 normalize rows (q, k)
    #pragma unroll
    for (int r = 0; r < 4; r++) {
      float ss = 0.f;
      #pragma unroll
      for (int ct = 0; ct < 16; ct++) ss += vals[ct][r] * vals[ct][r];
      ss += __shfl_xor(ss, 1); ss += __shfl_xor(ss, 2);
      ss += __shfl_xor(ss, 4); ss += __shfl_xor(ss, 8);
      float inv = 1.f / fmaxf(sqrtf(ss), 1e-12f);
      #pragma unroll
      for (int ct = 0; ct < 16; ct++) vals[ct][r] *= inv;
    }
  }
  #pragma unroll
  for (int ct = 0; ct < 16; ct++) {
    #pragma unroll
    for (int r = 0; r < 4; r++) {
      unsigned int bits = f2bf_bits(vals[ct][r]);
      unsigned int ob = (unsigned int)__shfl_xor((int)bits, 1);
      if (!(l & 1))
        *(unsigned int*)(dst + (size_t)(rw + g * 4 + r) * DDIM + ct * 16 + c) =
            bits | (ob << 16);
      if (out == 2)
        vstage[(ct * 16 + c) * 72 + (w * 16 + g * 4 + r)] = (unsigned short)bits;
    }
  }
  if (out == 2) {
    __syncthreads();
    #pragma unroll
    for (int p = 0; p < 8; p++) {
      int dd = (t >> 3) + p * 32;
      int ch = t & 7;
      *(uint4*)(vT + (size_t)dd * NROWS + row0 + ch * 8) =
          *(const uint4*)(vstage + dd * 72 + ch * 8);
    }
  }
}

// ---------------- kernel 2: fused relu-attention partials (32x32x16 MFMA) ----------------
// BM=128, 8 waves. S-phase: waves 4(qrow32) x 2(kcol32), swapped mfma(K,Q) -> S^T,
// lane&31 = qrow (lane-local row), per-lane scalar den, in-lane cvt_pk P-pack.
// PV-phase: waves 2(qrow64) x 4(dcol64), 2x2 32x32 tiles, 4 contraction chunks.
__global__ __launch_bounds__(512, 2) void attn_kernel(
    const unsigned short* __restrict__ qb, const unsigned short* __restrict__ kb,
    const unsigned short* __restrict__ vT,
    float* __restrict__ nump, float* __restrict__ denp)
{
  // 2x32KB K dbuf | 2x32KB vT dbuf | 16KB P ([128][64] bf16, XOR-swizzled)
  __shared__ __align__(16) char smem[147456];
  char* kbuf = smem;
  char* vbuf = smem + 65536;
  char* P    = smem + 131072;

  const int t = threadIdx.x;
  const int w = t >> 6, l = t & 63;
  const int l31 = l & 31, hi = l >> 5;
  const int sr = w >> 1, sc = w & 1;   // S-phase: qrow group (32), kcol group (32)
  const int pr = w >> 2, pc = w & 3;   // PV-phase: qrow group (64), dcol group (64)
  const int bid = blockIdx.x;
  const int split = bid & (KSPLIT - 1);
  const int mb = bid >> 2;
  const int q0 = mb * BM;
  const int kbase0 = split * (NROWS / KSPLIT);

  const char* kbc = (const char*)kb;
  const char* vtc = (const char*)vT;

  // hoist q fragments (B-operand): lane&31 = qrow, 16 chunks of K-dim = 64 VGPR
  bf16x8 qa[16];
  {
    const unsigned short* qrowp = qb + (size_t)(q0 + sr * 32 + l31) * DDIM + hi * 8;
    #pragma unroll
    for (int m = 0; m < 16; m++)
      qa[m] = *(const bf16x8*)(qrowp + m * 16);
  }

  f32x16 oacc[2][2];
  #pragma unroll
  for (int rt = 0; rt < 2; rt++)
    #pragma unroll
    for (int dt = 0; dt < 2; dt++)
      oacc[rt][dt] = (f32x16){0.f};
  float denl = 0.f;   // per-lane: qrow = sr*32 + l31, this wave's 16 kcols

  auto stage = [&](int buf, int it) {
    const int kbase = kbase0 + it * BK;
    const char* ksrc = kbc + (size_t)kbase * 512;
    #pragma unroll
    for (int i = 0; i < 4; i++) {
      int n = i * 512 + t;
      int row = n >> 5, slot = n & 31;
      gload_lds16(ksrc + row * 512 + ((slot ^ (row & 7)) * 16),
                  kbuf + buf * 32768 + i * 8192 + w * 1024);
    }
    const char* vsrc = vtc + (size_t)kbase * 2;
    #pragma unroll
    for (int i = 0; i < 4; i++) {
      int n = i * 512 + t;
      int dd = n >> 3, slot = n & 7;
      gload_lds16(vsrc + (size_t)dd * (NROWS * 2) + ((slot ^ (dd & 7)) * 16),
                  vbuf + buf * 32768 + i * 8192 + w * 1024);
    }
  };

  // prologue: stage tile 0 into buf 0
  stage(0, 0);
  asm volatile("s_waitcnt vmcnt(0)" ::: "memory");
  __builtin_amdgcn_sched_barrier(0);
  __builtin_amdgcn_s_barrier();
  __builtin_amdgcn_sched_barrier(0);

  for (int it = 0; it < NT; ++it) {
    const int cur = it & 1;
    if (it + 1 < NT) stage(cur ^ 1, it + 1);
    __builtin_amdgcn_sched_barrier(0);

    // ---- S^T = K.Q^T: this wave's 32 kcols x 32 qrows, one 32x32 tile ----
    const char* kcur = kbuf + cur * 32768;
    const int krl = sc * 32 + l31;
    f32x16 sacc = {0.f};
    #pragma unroll
    for (int m = 0; m < 16; m++) {
      bf16x8 kf = *(const bf16x8*)(kcur + krl * 512 + ((m * 32 + hi * 16) ^ ((krl & 7) << 4)));
      sacc = __builtin_amdgcn_mfma_f32_32x32x16_bf16(kf, qa[m], sacc, 0, 0, 0);
    }
    // relu + per-lane den + in-lane bf16 pack to P (lane's qrow, 16 kcols)
    {
      const int qrow = sr * 32 + l31;
      char* prow = P + qrow * 128;
      const int swz = (qrow & 7) << 4;
      #pragma unroll
      for (int j = 0; j < 4; j++) {
        float v0 = fmaxf(sacc[4 * j + 0], 0.f);
        float v1 = fmaxf(sacc[4 * j + 1], 0.f);
        float v2 = fmaxf(sacc[4 * j + 2], 0.f);
        float v3 = fmaxf(sacc[4 * j + 3], 0.f);
        denl += (v0 + v1) + (v2 + v3);
        uint2 d2;
        d2.x = pack2bf(v0, v1);
        d2.y = pack2bf(v2, v3);
        // kcol base = sc*32 + j*8 + hi*4  -> byte col = sc*64 + j*16 + hi*8
        *(uint2*)(prow + ((sc * 64 + j * 16 + hi * 8) ^ swz)) = d2;
      }
    }
    // P visibility barrier — LDS-only drain, prefetch loads stay in flight
    asm volatile("s_waitcnt lgkmcnt(0)" ::: "memory");
    __builtin_amdgcn_sched_barrier(0);
    __builtin_amdgcn_s_barrier();
    __builtin_amdgcn_sched_barrier(0);

    // ---- PV: this wave's 64 qrows x 64 d-cols as 2x2 32x32 tiles ----
    const char* vcur = vbuf + cur * 32768;
    #pragma unroll
    for (int ch = 0; ch < 4; ch++) {
      bf16x8 pa[2], vf[2];
      #pragma unroll
      for (int rt = 0; rt < 2; rt++) {
        int qrow = pr * 64 + rt * 32 + l31;
        pa[rt] = *(const bf16x8*)(P + qrow * 128 +
                                  ((ch * 32 + hi * 16) ^ ((qrow & 7) << 4)));
      }
      #pragma unroll
      for (int dt = 0; dt < 2; dt++) {
        int dl = pc * 64 + dt * 32 + l31;
        vf[dt] = *(const bf16x8*)(vcur + dl * 128 +
                                  ((ch * 32 + hi * 16) ^ ((dl & 7) << 4)));
      }
      #pragma unroll
      for (int rt = 0; rt < 2; rt++)
        #pragma unroll
        for (int dt = 0; dt < 2; dt++)
          oacc[rt][dt] = __builtin_amdgcn_mfma_f32_32x32x16_bf16(pa[rt], vf[dt],
                                                                 oacc[rt][dt], 0, 0, 0);
    }
    // end-of-tile: next buffers staged (single counted drain point per iter)
    asm volatile("s_waitcnt vmcnt(0)" ::: "memory");
    __builtin_amdgcn_sched_barrier(0);
    __builtin_amdgcn_s_barrier();
    __builtin_amdgcn_sched_barrier(0);
  }

  // write numerator partials (fp32). C layout: col=lane&31, row=(r&3)+8*(r>>2)+4*hi
  float* np = nump + (size_t)split * NROWS * DDIM;
  #pragma unroll
  for (int rt = 0; rt < 2; rt++)
    #pragma unroll
    for (int dt = 0; dt < 2; dt++)
      #pragma unroll
      for (int r = 0; r < 16; r++) {
        int rowg = q0 + pr * 64 + rt * 32 + (r & 3) + 8 * (r >> 2) + 4 * hi;
        int col  = pc * 64 + dt * 32 + l31;
        np[(size_t)rowg * DDIM + col] = oacc[rt][dt][r];
      }
  // den: lanes l and l+32 hold the same qrow's two kcol-halves
  {
    float d = denl;
    d += __shfl_xor(d, 32);
    if (l < 32)
      denp[((size_t)split * 2 + sc) * NROWS + q0 + sr * 32 + l] = d;
  }
}

// ---------------- kernel 3: combine partials, diagonal fix, output ----------------
__global__ __launch_bounds__(256) void combine_kernel(
    const float* __restrict__ x, const unsigned short* __restrict__ qb,
    const unsigned short* __restrict__ kb, const unsigned short* __restrict__ vb,
    const float* __restrict__ nump, const float* __restrict__ denp,
    float* __restrict__ out)
{
  const int t = threadIdx.x;
  const int w = t >> 6, l = t & 63;
  const int i = blockIdx.x * 4 + w;

  ushort4 q4 = *(const ushort4*)(qb + (size_t)i * DDIM + l * 4);
  ushort4 k4 = *(const ushort4*)(kb + (size_t)i * DDIM + l * 4);
  float s = bf2f(q4.x) * bf2f(k4.x) + bf2f(q4.y) * bf2f(k4.y)
          + bf2f(q4.z) * bf2f(k4.z) + bf2f(q4.w) * bf2f(k4.w);
  #pragma unroll
  for (int m = 1; m < 64; m <<= 1) s += __shfl_xor(s, m);
  float r  = fmaxf(s, 0.f);
  float rb = bf2f(f2bf_bits(r));   // match attn's bf16-rounded P value

  float den = 0.f;
  #pragma unroll
  for (int sp = 0; sp < KSPLIT * 2; sp++)
    den += denp[(size_t)sp * NROWS + i];
  float inv = 1.f / fmaxf(den - rb, 1e-12f);

  const int d0 = l * 4;
  float4 acc = *(const float4*)(nump + (size_t)i * DDIM + d0);
  #pragma unroll
  for (int sp = 1; sp < KSPLIT; sp++) {
    float4 a2 = *(const float4*)(nump + (size_t)sp * NROWS * DDIM + (size_t)i * DDIM + d0);
    acc.x += a2.x; acc.y += a2.y; acc.z += a2.z; acc.w += a2.w;
  }
  ushort4 v4 = *(const ushort4*)(vb + (size_t)i * DDIM + d0);
  float4 xx = *(const float4*)(x + (size_t)i * DDIM + d0);
  float4 o;
  o.x = (acc.x - rb * bf2f(v4.x)) * inv + xx.x;
  o.y = (acc.y - rb * bf2f(v4.y)) * inv + xx.y;
  o.z = (acc.z - rb * bf2f(v4.z)) * inv + xx.z;
  o.w = (acc.w - rb * bf2f(v4.w)) * inv + xx.w;
  *(float4*)(out + (size_t)i * DDIM + d0) = o;
}

extern "C" void kernel_launch(void* const* d_in, const int* in_sizes, int n_in,
                              void* d_out, int out_size, void* d_ws, size_t ws_size,
                              hipStream_t stream)
{
  const float* x  = (const float*)d_in[0];
  const float* Wq = (const float*)d_in[1];
  const float* bq = (const float*)d_in[2];
  const float* Wk = (const float*)d_in[3];
  const float* bk = (const float*)d_in[4];
  const float* Wv = (const float*)d_in[5];
  const float* bv = (const float*)d_in[6];

  char* ws = (char*)d_ws;
  unsigned short* Wb  = (unsigned short*)(ws + 0);          // 384 KB (3 matrices)
  unsigned short* qb  = (unsigned short*)(ws + 393216);     // 4 MB
  unsigned short* kb  = (unsigned short*)(ws + 4587520);    // 4 MB
  unsigned short* vb  = (unsigned short*)(ws + 8781824);    // 4 MB
  unsigned short* vT  = (unsigned short*)(ws + 12976128);   // 4 MB
  float* nump = (float*)(ws + 17170432);                    // 32 MB (4 splits)
  float* denp = (float*)(ws + 50724864);                    // 256 KB (8 slices)

  convert_kernel<<<192, 256, 0, stream>>>(Wq, Wk, Wv, Wb);
  qkv_kernel<<<384, 256, 0, stream>>>(bq, bk, bv, x, Wb, qb, kb, vb, vT);
  attn_kernel<<<(NROWS / BM) * KSPLIT, 512, 0, stream>>>(qb, kb, vT, nump, denp);
  combine_kernel<<<NROWS / 4, 256, 0, stream>>>(x, qb, kb, vb, nump, denp, (float*)d_out);
}